// Round 1
// baseline (292.549 us; speedup 1.0000x reference)
//
#include <hip/hip_runtime.h>
#include <stdint.h>

// B=2, S=2048, D=1024, H=16, dh=64, THETA=10000
// Pipeline: cast -> QKV gemm (bf16) -> rope/repack -> flash attn -> out gemm (fp32 out)

typedef __attribute__((ext_vector_type(8))) __bf16 bf16x8;
typedef __attribute__((ext_vector_type(8))) unsigned short u16x8;
typedef __attribute__((ext_vector_type(4))) float f32x4;

__device__ inline unsigned short f2bf(float f){
  unsigned int u = __float_as_uint(f);
  unsigned int r = (u + 0x7FFFu + ((u >> 16) & 1u)) >> 16;  // RNE
  return (unsigned short)r;
}
__device__ inline float bf2f(unsigned short u){
  return __uint_as_float(((unsigned int)u) << 16);
}

__global__ __launch_bounds__(256) void cast_kernel(const float* __restrict__ in,
                                                   unsigned short* __restrict__ out, int n4){
  int i = blockIdx.x * 256 + threadIdx.x;
  if (i >= n4) return;
  float4 v = ((const float4*)in)[i];
  ushort4 o;
  o.x = f2bf(v.x); o.y = f2bf(v.y); o.z = f2bf(v.z); o.w = f2bf(v.w);
  ((ushort4*)out)[i] = o;
}

// C[M,N] = A[M,K] * W[N,K]^T  (both row-major bf16, K contiguous). 128x128 tile, BK=64.
template<int WRITE_BF16>
__global__ __launch_bounds__(256) void gemm_bt(const unsigned short* __restrict__ A,
                                               const unsigned short* __restrict__ W,
                                               void* __restrict__ Cp,
                                               int M, int N, int K){
  __shared__ __align__(16) unsigned short As[128*72];  // +8 pad: 2-way bank alias (free)
  __shared__ __align__(16) unsigned short Bs[128*72];
  const int tid  = threadIdx.x;
  const int lane = tid & 63, wave = tid >> 6;
  const int wr = wave >> 1, wc = wave & 1;
  const int quad = lane >> 4, c = lane & 15;
  const int m0 = blockIdx.y * 128, n0 = blockIdx.x * 128;

  const f32x4 z4 = {0.f, 0.f, 0.f, 0.f};
  f32x4 acc[4][4];
  #pragma unroll
  for (int i = 0; i < 4; i++)
    #pragma unroll
    for (int j = 0; j < 4; j++) acc[i][j] = z4;

  const int nk = K >> 6;
  for (int kt = 0; kt < nk; kt++){
    const int k0 = kt << 6;
    #pragma unroll
    for (int i = 0; i < 4; i++){
      int ch = tid + i * 256;          // 1024 chunks of 16B per tile
      int row = ch >> 3, sub = ch & 7;
      *(u16x8*)&As[row*72 + sub*8] = *(const u16x8*)&A[(size_t)(m0+row)*K + k0 + sub*8];
      *(u16x8*)&Bs[row*72 + sub*8] = *(const u16x8*)&W[(size_t)(n0+row)*K + k0 + sub*8];
    }
    __syncthreads();
    #pragma unroll
    for (int ks = 0; ks < 2; ks++){
      bf16x8 af[4], bfr[4];
      #pragma unroll
      for (int i = 0; i < 4; i++)
        af[i] = *(const bf16x8*)&As[(wr*64 + i*16 + c)*72 + ks*32 + quad*8];
      #pragma unroll
      for (int j = 0; j < 4; j++)
        bfr[j] = *(const bf16x8*)&Bs[(wc*64 + j*16 + c)*72 + ks*32 + quad*8];
      #pragma unroll
      for (int i = 0; i < 4; i++)
        #pragma unroll
        for (int j = 0; j < 4; j++)
          acc[i][j] = __builtin_amdgcn_mfma_f32_16x16x32_bf16(af[i], bfr[j], acc[i][j], 0, 0, 0);
    }
    __syncthreads();
  }
  #pragma unroll
  for (int i = 0; i < 4; i++)
    #pragma unroll
    for (int j = 0; j < 4; j++)
      #pragma unroll
      for (int r = 0; r < 4; r++){
        int row = m0 + wr*64 + i*16 + quad*4 + r;   // C/D: row = quad*4+reg
        int col = n0 + wc*64 + j*16 + c;            //      col = lane&15
        float v = acc[i][j][r];
        if (WRITE_BF16) ((unsigned short*)Cp)[(size_t)row*N + col] = f2bf(v);
        else            ((float*)Cp)[(size_t)row*N + col] = v;
      }
}

// QKV (4096 x 3072 bf16, col = t*1024 + h*64 + d)  ->  Qh/Kh/Vh [H][B][S][64] bf16, rope on Q,K
__global__ __launch_bounds__(256) void rope_kernel(const unsigned short* __restrict__ QKV,
                                                   unsigned short* __restrict__ Qh,
                                                   unsigned short* __restrict__ Kh,
                                                   unsigned short* __restrict__ Vh){
  int tid = blockIdx.x * 256 + threadIdx.x;     // 2M threads: (b,s,h,p)
  int p = tid & 31;
  int h = (tid >> 5) & 15;
  int s = (tid >> 9) & 2047;
  int b = tid >> 20;
  size_t ibase = (size_t)(b*2048 + s) * 3072 + h*64 + 2*p;
  ushort2 q2 = *(const ushort2*)&QKV[ibase];
  ushort2 k2 = *(const ushort2*)&QKV[ibase + 1024];
  ushort2 v2 = *(const ushort2*)&QKV[ibase + 2048];
  float freq = __expf(-(float)p * (9.210340371976184f / 32.0f));  // theta^(-p/32)
  float ang = (float)s * freq;
  float cs = cosf(ang), sn = sinf(ang);
  float qe = bf2f(q2.x), qo = bf2f(q2.y);
  float ke = bf2f(k2.x), ko = bf2f(k2.y);
  ushort2 qn, kn;
  qn.x = f2bf(qe*cs - qo*sn); qn.y = f2bf(qe*sn + qo*cs);
  kn.x = f2bf(ke*cs - ko*sn); kn.y = f2bf(ke*sn + ko*cs);
  size_t obase = (size_t)((h*2 + b)*2048 + s) * 64 + 2*p;
  *(ushort2*)&Qh[obase] = qn;
  *(ushort2*)&Kh[obase] = kn;
  *(ushort2*)&Vh[obase] = v2;
}

// Flash attention, causal. BQ=128 (4 waves x 32 rows), BKV=64. AO[b][s][h*64+d] bf16.
__global__ __launch_bounds__(256) void attn_kernel(const unsigned short* __restrict__ Qh,
                                                   const unsigned short* __restrict__ Kh,
                                                   const unsigned short* __restrict__ Vh,
                                                   unsigned short* __restrict__ AO){
  __shared__ __align__(16) unsigned short Qs [128*72];
  __shared__ __align__(16) unsigned short Ks [64*72];
  __shared__ __align__(16) unsigned short Vts[64*72];   // V transposed: [d][kv]
  __shared__ __align__(16) unsigned short Ps [128*72];  // P in A-layout staging
  const int qt = blockIdx.x;   // 0..15
  const int b  = blockIdx.y;   // 0..1
  const int h  = blockIdx.z;   // 0..15
  const int q0 = qt * 128;
  const int tid = threadIdx.x;
  const int lane = tid & 63, wave = tid >> 6;
  const int quad = lane >> 4, c = lane & 15;
  const size_t hb = (size_t)(h*2 + b) * 2048 * 64;
  const unsigned short* qp = Qh + hb;
  const unsigned short* kp = Kh + hb;
  const unsigned short* vp = Vh + hb;

  #pragma unroll
  for (int i = 0; i < 4; i++){
    int ch = tid + i * 256;
    int row = ch >> 3, sub = ch & 7;
    *(u16x8*)&Qs[row*72 + sub*8] = *(const u16x8*)&qp[(size_t)(q0+row)*64 + sub*8];
  }

  const f32x4 z4 = {0.f, 0.f, 0.f, 0.f};
  float mi[2][4], li[2][4];
  f32x4 Oa[2][4];
  #pragma unroll
  for (int i = 0; i < 2; i++)
    #pragma unroll
    for (int r = 0; r < 4; r++){ mi[i][r] = -1e30f; li[i][r] = 0.f; }
  #pragma unroll
  for (int i = 0; i < 2; i++)
    #pragma unroll
    for (int dt = 0; dt < 4; dt++) Oa[i][dt] = z4;

  const int nkt = 2*qt + 2;
  for (int kt = 0; kt < nkt; kt++){
    const int kv0 = kt * 64;
    __syncthreads();   // prev iter done reading Ks/Vts/Ps (also fences Q staging on iter 0)
    #pragma unroll
    for (int i = 0; i < 2; i++){
      int ch = tid + i * 256;
      int row = ch >> 3, sub = ch & 7;
      *(u16x8*)&Ks[row*72 + sub*8] = *(const u16x8*)&kp[(size_t)(kv0+row)*64 + sub*8];
      u16x8 v = *(const u16x8*)&vp[(size_t)(kv0+row)*64 + sub*8];
      #pragma unroll
      for (int j = 0; j < 8; j++)
        Vts[(sub*8 + j)*72 + row] = v[j];
    }
    __syncthreads();

    // S = Q K^T for this wave's 32 rows (2 row-tiles x 4 col-tiles)
    f32x4 sa[2][4];
    #pragma unroll
    for (int i = 0; i < 2; i++)
      #pragma unroll
      for (int ct = 0; ct < 4; ct++) sa[i][ct] = z4;
    #pragma unroll
    for (int ks = 0; ks < 2; ks++){
      bf16x8 af[2], bfr[4];
      #pragma unroll
      for (int i = 0; i < 2; i++)
        af[i] = *(const bf16x8*)&Qs[(wave*32 + i*16 + c)*72 + ks*32 + quad*8];
      #pragma unroll
      for (int ct = 0; ct < 4; ct++)
        bfr[ct] = *(const bf16x8*)&Ks[(ct*16 + c)*72 + ks*32 + quad*8];
      #pragma unroll
      for (int i = 0; i < 2; i++)
        #pragma unroll
        for (int ct = 0; ct < 4; ct++)
          sa[i][ct] = __builtin_amdgcn_mfma_f32_16x16x32_bf16(af[i], bfr[ct], sa[i][ct], 0, 0, 0);
    }
    const float scale = 0.125f;
    if (kt >= 2*qt){  // diagonal tiles need causal mask
      #pragma unroll
      for (int i = 0; i < 2; i++)
        #pragma unroll
        for (int ct = 0; ct < 4; ct++)
          #pragma unroll
          for (int r = 0; r < 4; r++){
            int rowg = q0 + wave*32 + i*16 + quad*4 + r;
            int colg = kv0 + ct*16 + c;
            float v = sa[i][ct][r] * scale;
            sa[i][ct][r] = (colg > rowg) ? -1e30f : v;
          }
    } else {
      #pragma unroll
      for (int i = 0; i < 2; i++)
        #pragma unroll
        for (int ct = 0; ct < 4; ct++)
          #pragma unroll
          for (int r = 0; r < 4; r++) sa[i][ct][r] *= scale;
    }
    // row max across 4 col-tiles then across the 16 lanes sharing a row
    float mx[2][4];
    #pragma unroll
    for (int i = 0; i < 2; i++)
      #pragma unroll
      for (int r = 0; r < 4; r++){
        float v = sa[i][0][r];
        v = fmaxf(v, sa[i][1][r]); v = fmaxf(v, sa[i][2][r]); v = fmaxf(v, sa[i][3][r]);
        #pragma unroll
        for (int off = 1; off < 16; off <<= 1)
          v = fmaxf(v, __shfl_xor(v, off, 64));
        mx[i][r] = v;
      }
    float al[2][4];
    #pragma unroll
    for (int i = 0; i < 2; i++)
      #pragma unroll
      for (int r = 0; r < 4; r++){
        float mn = fmaxf(mi[i][r], mx[i][r]);
        al[i][r] = __expf(mi[i][r] - mn);
        mi[i][r] = mn;
      }
    float rs[2][4] = {};
    #pragma unroll
    for (int i = 0; i < 2; i++)
      #pragma unroll
      for (int ct = 0; ct < 4; ct++)
        #pragma unroll
        for (int r = 0; r < 4; r++){
          float p = __expf(sa[i][ct][r] - mi[i][r]);
          rs[i][r] += p;
          Ps[(wave*32 + i*16 + quad*4 + r)*72 + ct*16 + c] = f2bf(p);
        }
    #pragma unroll
    for (int i = 0; i < 2; i++)
      #pragma unroll
      for (int r = 0; r < 4; r++){
        float v = rs[i][r];
        #pragma unroll
        for (int off = 1; off < 16; off <<= 1)
          v += __shfl_xor(v, off, 64);
        li[i][r] = li[i][r] * al[i][r] + v;
      }
    #pragma unroll
    for (int i = 0; i < 2; i++)
      #pragma unroll
      for (int dt = 0; dt < 4; dt++)
        #pragma unroll
        for (int r = 0; r < 4; r++)
          Oa[i][dt][r] *= al[i][r];
    __syncthreads();   // Ps visible (wave-local rows, but fence LDS write->read)
    // O += P V   (A = Ps rows, B = Vts[d][kv] as gemm_bt W)
    #pragma unroll
    for (int ks = 0; ks < 2; ks++){
      bf16x8 af[2], bfr[4];
      #pragma unroll
      for (int i = 0; i < 2; i++)
        af[i] = *(const bf16x8*)&Ps[(wave*32 + i*16 + c)*72 + ks*32 + quad*8];
      #pragma unroll
      for (int dt = 0; dt < 4; dt++)
        bfr[dt] = *(const bf16x8*)&Vts[(dt*16 + c)*72 + ks*32 + quad*8];
      #pragma unroll
      for (int i = 0; i < 2; i++)
        #pragma unroll
        for (int dt = 0; dt < 4; dt++)
          Oa[i][dt] = __builtin_amdgcn_mfma_f32_16x16x32_bf16(af[i], bfr[dt], Oa[i][dt], 0, 0, 0);
    }
  }
  #pragma unroll
  for (int i = 0; i < 2; i++)
    #pragma unroll
    for (int dt = 0; dt < 4; dt++)
      #pragma unroll
      for (int r = 0; r < 4; r++){
        float v = Oa[i][dt][r] / li[i][r];
        int srow = q0 + wave*32 + i*16 + quad*4 + r;
        int col  = h*64 + dt*16 + c;
        AO[(size_t)(b*2048 + srow)*1024 + col] = f2bf(v);
      }
}

extern "C" void kernel_launch(void* const* d_in, const int* in_sizes, int n_in,
                              void* d_out, int out_size, void* d_ws, size_t ws_size,
                              hipStream_t stream){
  const float* X    = (const float*)d_in[0];   // 2*2048*1024
  const float* Wqkv = (const float*)d_in[1];   // 3072*1024
  const float* Wo   = (const float*)d_in[2];   // 1024*1024
  float* out = (float*)d_out;                  // 2*2048*1024 fp32
  char* ws = (char*)d_ws;
  // workspace map (72 MB total)
  unsigned short* Xb    = (unsigned short*)(ws);                       // 8 MB
  unsigned short* Wqkvb = (unsigned short*)(ws + (size_t)8  * 1048576); // 6 MB
  unsigned short* Wob   = (unsigned short*)(ws + (size_t)14 * 1048576); // 2 MB
  unsigned short* QKVb  = (unsigned short*)(ws + (size_t)16 * 1048576); // 24 MB
  unsigned short* Qh    = (unsigned short*)(ws + (size_t)40 * 1048576); // 8 MB
  unsigned short* Kh    = (unsigned short*)(ws + (size_t)48 * 1048576); // 8 MB
  unsigned short* Vh    = (unsigned short*)(ws + (size_t)56 * 1048576); // 8 MB
  unsigned short* AO    = (unsigned short*)(ws + (size_t)64 * 1048576); // 8 MB

  cast_kernel<<<4096, 256, 0, stream>>>(X,    Xb,    1048576);
  cast_kernel<<<3072, 256, 0, stream>>>(Wqkv, Wqkvb, 786432);
  cast_kernel<<<1024, 256, 0, stream>>>(Wo,   Wob,   262144);
  gemm_bt<1><<<dim3(24, 32), 256, 0, stream>>>(Xb, Wqkvb, QKVb, 4096, 3072, 1024);
  rope_kernel<<<8192, 256, 0, stream>>>(QKVb, Qh, Kh, Vh);
  attn_kernel<<<dim3(16, 2, 16), 256, 0, stream>>>(Qh, Kh, Vh, AO);
  gemm_bt<0><<<dim3(8, 32), 256, 0, stream>>>(AO, Wob, out, 4096, 1024, 1024);
}

// Round 2
// 216.228 us; speedup vs baseline: 1.3530x; 1.3530x over previous
//
#include <hip/hip_runtime.h>
#include <stdint.h>

// B=2, S=2048, D=1024, H=16, dh=64, THETA=10000
// cast -> QKV gemm (async-LDS, swizzled) -> rope(Q,K) + vtrans(V, permuted) ->
// flash attn (BQ=128, BKV=128, 8 waves, packed-P) -> out gemm (fp32 out)

typedef __attribute__((ext_vector_type(8))) __bf16 bf16x8;
typedef __attribute__((ext_vector_type(8))) unsigned short u16x8;
typedef __attribute__((ext_vector_type(4))) float f32x4;

__device__ __forceinline__ unsigned short f2bf(float f){
  unsigned int u = __float_as_uint(f);
  unsigned int r = (u + 0x7FFFu + ((u >> 16) & 1u)) >> 16;  // RNE
  return (unsigned short)r;
}
__device__ __forceinline__ float bf2f(unsigned short u){
  return __uint_as_float(((unsigned int)u) << 16);
}

// async global->LDS, 16B per lane; LDS dest = wave-uniform base + lane*16
__device__ __forceinline__ void gld16(const unsigned short* g, unsigned short* l){
  __builtin_amdgcn_global_load_lds((const __attribute__((address_space(1))) unsigned int*)g,
                                   (__attribute__((address_space(3))) unsigned int*)l,
                                   16, 0, 0);
}

__global__ __launch_bounds__(256) void cast_kernel(const float* __restrict__ in,
                                                   unsigned short* __restrict__ out, int n4){
  int i = blockIdx.x * 256 + threadIdx.x;
  if (i >= n4) return;
  float4 v = ((const float4*)in)[i];
  ushort4 o;
  o.x = f2bf(v.x); o.y = f2bf(v.y); o.z = f2bf(v.z); o.w = f2bf(v.w);
  ((ushort4*)out)[i] = o;
}

// C[M,N] = A[M,K] * W[N,K]^T, bf16, 128x128 tile, BK=64.
// LDS unpadded 128x64; 16B chunk at (row, pos) holds global chunk (row, pos^(row&7)).
template<int WRITE_BF16>
__global__ __launch_bounds__(256) void gemm_bt(const unsigned short* __restrict__ A,
                                               const unsigned short* __restrict__ W,
                                               void* __restrict__ Cp,
                                               int M, int N, int K){
  __shared__ __align__(16) unsigned short As[128*64];
  __shared__ __align__(16) unsigned short Bs[128*64];
  const int tid  = threadIdx.x;
  const int lane = tid & 63, wave = tid >> 6;
  const int wr = wave >> 1, wc = wave & 1;
  const int quad = lane >> 4, c = lane & 15;
  const int m0 = blockIdx.y * 128, n0 = blockIdx.x * 128;

  const f32x4 z4 = {0.f, 0.f, 0.f, 0.f};
  f32x4 acc[4][4];
  #pragma unroll
  for (int i = 0; i < 4; i++)
    #pragma unroll
    for (int j = 0; j < 4; j++) acc[i][j] = z4;

  const int nk = K >> 6;
  for (int kt = 0; kt < nk; kt++){
    const int k0 = kt << 6;
    #pragma unroll
    for (int p = 0; p < 4; p++){
      int blk = p*4 + wave;            // 16 blocks of 64 chunks
      int L = blk*64 + lane;           // chunk 0..1023
      int row = L >> 3;
      int sub = (L & 7) ^ (row & 7);   // swizzled global source
      gld16(&A[(size_t)(m0+row)*K + k0 + sub*8], &As[blk*512]);
      gld16(&W[(size_t)(n0+row)*K + k0 + sub*8], &Bs[blk*512]);
    }
    __syncthreads();
    #pragma unroll
    for (int ks = 0; ks < 2; ks++){
      bf16x8 af[4], bfr[4];
      #pragma unroll
      for (int i = 0; i < 4; i++){
        int row = wr*64 + i*16 + c;
        int pos = (ks*4 + quad) ^ (c & 7);
        af[i] = *(const bf16x8*)&As[row*64 + pos*8];
      }
      #pragma unroll
      for (int j = 0; j < 4; j++){
        int row = wc*64 + j*16 + c;
        int pos = (ks*4 + quad) ^ (c & 7);
        bfr[j] = *(const bf16x8*)&Bs[row*64 + pos*8];
      }
      #pragma unroll
      for (int i = 0; i < 4; i++)
        #pragma unroll
        for (int j = 0; j < 4; j++)
          acc[i][j] = __builtin_amdgcn_mfma_f32_16x16x32_bf16(af[i], bfr[j], acc[i][j], 0, 0, 0);
    }
    __syncthreads();
  }
  #pragma unroll
  for (int i = 0; i < 4; i++)
    #pragma unroll
    for (int j = 0; j < 4; j++)
      #pragma unroll
      for (int r = 0; r < 4; r++){
        int row = m0 + wr*64 + i*16 + quad*4 + r;
        int col = n0 + wc*64 + j*16 + c;
        float v = acc[i][j][r];
        if (WRITE_BF16) ((unsigned short*)Cp)[(size_t)row*N + col] = f2bf(v);
        else            ((float*)Cp)[(size_t)row*N + col] = v;
      }
}

// rope on Q,K: QKV (4096 x 3072) -> Qh/Kh [h][b][s][64]
__global__ __launch_bounds__(256) void rope_kernel(const unsigned short* __restrict__ QKV,
                                                   unsigned short* __restrict__ Qh,
                                                   unsigned short* __restrict__ Kh){
  int tid = blockIdx.x * 256 + threadIdx.x;     // 2M threads: (b,s,h,p)
  int p = tid & 31;
  int h = (tid >> 5) & 15;
  int s = (tid >> 9) & 2047;
  int b = tid >> 20;
  size_t ibase = (size_t)(b*2048 + s) * 3072 + h*64 + 2*p;
  ushort2 q2 = *(const ushort2*)&QKV[ibase];
  ushort2 k2 = *(const ushort2*)&QKV[ibase + 1024];
  float freq = __expf(-(float)p * (9.210340371976184f / 32.0f));  // theta^(-p/32)
  float ang = (float)s * freq;
  float cs = cosf(ang), sn = sinf(ang);
  float qe = bf2f(q2.x), qo = bf2f(q2.y);
  float ke = bf2f(k2.x), ko = bf2f(k2.y);
  ushort2 qn, kn;
  qn.x = f2bf(qe*cs - qo*sn); qn.y = f2bf(qe*sn + qo*cs);
  kn.x = f2bf(ke*cs - ko*sn); kn.y = f2bf(ke*sn + ko*cs);
  size_t obase = (size_t)((h*2 + b)*2048 + s) * 64 + 2*p;
  *(ushort2*)&Qh[obase] = qn;
  *(ushort2*)&Kh[obase] = kn;
}

// V -> Vtp [h][b][d=64][S], columns within each 128-s block permuted:
// Vtp[d][blk*128 + col'] = V[blk*128 + (col'&7)*16 + (col'>>3)][d]
__global__ __launch_bounds__(256) void vtrans_kernel(const unsigned short* __restrict__ QKV,
                                                     unsigned short* __restrict__ Vtp){
  __shared__ unsigned short Vs[128*72];
  const int st = blockIdx.x, b = blockIdx.y, h = blockIdx.z;
  const int s0 = st * 128;
  const int tid = threadIdx.x;
  #pragma unroll
  for (int it = 0; it < 4; it++){
    int L = it*256 + tid;               // 1024 chunks of 8
    int r = L >> 3, sub = L & 7;
    *(u16x8*)&Vs[r*72 + sub*8] =
      *(const u16x8*)&QKV[(size_t)(b*2048 + s0 + r)*3072 + 2048 + h*64 + sub*8];
  }
  __syncthreads();
  const size_t obase = (size_t)((h*2 + b) * 64) * 2048;
  #pragma unroll
  for (int it = 0; it < 4; it++){
    int L = it*256 + tid;               // d(64) x s8(16)
    int d = L >> 4, s8 = L & 15;
    u16x8 pk;
    #pragma unroll
    for (int j = 0; j < 8; j++)
      pk[j] = Vs[(j*16 + s8)*72 + d];   // kv(col'=s8*8+j) = j*16+s8
    *(u16x8*)&Vtp[obase + (size_t)d*2048 + s0 + s8*8] = pk;
  }
}

// Flash attention, causal. BQ=128 (8 waves x 16 rows), BKV=128.
// Ks[kv][d] swizzled; Vts[d][col'] swizzled; Ps[q][col'] swizzled, wave-private rows.
__global__ __launch_bounds__(512, 4) void attn_kernel(const unsigned short* __restrict__ Qh,
                                                      const unsigned short* __restrict__ Kh,
                                                      const unsigned short* __restrict__ Vtp,
                                                      unsigned short* __restrict__ AO){
  __shared__ __align__(16) unsigned short Ks [128*64];
  __shared__ __align__(16) unsigned short Vts[64*128];
  __shared__ __align__(16) unsigned short Ps [128*128];
  const int bx = blockIdx.x;                 // 512 blocks
  const int g  = bx >> 5;                    // work pairing: (15-g, g) sums to 17 iters
  const int qt = (g < 8) ? (15 - g) : (g - 8);
  const int bh = bx & 31;
  const int h = bh >> 1, b = bh & 1;
  const int q0 = qt * 128;
  const int tid = threadIdx.x;
  const int lane = tid & 63, w = tid >> 6;   // 8 waves, wave w: q rows q0+w*16..+16
  const int quad = lane >> 4, c = lane & 15;
  const size_t hb = (size_t)(h*2 + b) * 2048 * 64;
  const unsigned short* qp = Qh + hb;
  const unsigned short* kp = Kh + hb;
  const unsigned short* vp = Vtp + hb;

  bf16x8 qf[2];                               // Q fragments in registers
  #pragma unroll
  for (int ks = 0; ks < 2; ks++)
    qf[ks] = *(const bf16x8*)&qp[(size_t)(q0 + w*16 + c)*64 + ks*32 + quad*8];

  const f32x4 z4 = {0.f, 0.f, 0.f, 0.f};
  float mi[4], li[4];
  f32x4 Oa[4];
  #pragma unroll
  for (int r = 0; r < 4; r++){ mi[r] = -3.0e38f; li[r] = 0.f; }
  #pragma unroll
  for (int dt = 0; dt < 4; dt++) Oa[dt] = z4;

  const int nkt = qt + 1;
  for (int kt = 0; kt < nkt; kt++){
    const int kv0 = kt * 128;
    __syncthreads();                          // all waves done with prev Ks/Vts
    #pragma unroll
    for (int p = 0; p < 2; p++){
      int blk = p*8 + w;                      // 16 blocks of 64 chunks
      int L = blk*64 + lane;
      {   // K tile: 128 rows x 8 chunks
        int row = L >> 3;
        int sub = (L & 7) ^ (row & 7);
        gld16(&kp[(size_t)(kv0 + row)*64 + sub*8], &Ks[blk*512]);
      }
      {   // Vt tile: 64 d-rows x 16 chunks
        int d = L >> 4;
        int pos = L & 15;
        int s8 = (pos & 8) | ((pos & 7) ^ (d & 7));
        gld16(&vp[(size_t)d*2048 + kv0 + s8*8], &Vts[blk*512]);
      }
    }
    __syncthreads();

    // S = Q K^T: 8 col tiles of 16
    f32x4 sa[8];
    #pragma unroll
    for (int ct = 0; ct < 8; ct++) sa[ct] = z4;
    #pragma unroll
    for (int ks = 0; ks < 2; ks++)
      #pragma unroll
      for (int ct = 0; ct < 8; ct++){
        int row = ct*16 + c;
        int pos = (ks*4 + quad) ^ (c & 7);
        bf16x8 kf = *(const bf16x8*)&Ks[row*64 + pos*8];
        sa[ct] = __builtin_amdgcn_mfma_f32_16x16x32_bf16(qf[ks], kf, sa[ct], 0, 0, 0);
      }

    const float sc2 = 0.18033688011112042f;   // log2(e)/8
    if (kt == qt){
      #pragma unroll
      for (int ct = 0; ct < 8; ct++)
        #pragma unroll
        for (int r = 0; r < 4; r++){
          int rowl = w*16 + quad*4 + r;       // kv0==q0: compare locally
          int coll = ct*16 + c;
          float v = sa[ct][r] * sc2;
          sa[ct][r] = (coll > rowl) ? -3.0e38f : v;
        }
    } else {
      #pragma unroll
      for (int ct = 0; ct < 8; ct++)
        #pragma unroll
        for (int r = 0; r < 4; r++) sa[ct][r] *= sc2;
    }

    float mx[4], al[4], rs[4];
    #pragma unroll
    for (int r = 0; r < 4; r++){
      float v = sa[0][r];
      #pragma unroll
      for (int ct = 1; ct < 8; ct++) v = fmaxf(v, sa[ct][r]);
      #pragma unroll
      for (int off = 1; off < 16; off <<= 1)
        v = fmaxf(v, __shfl_xor(v, off, 64));
      mx[r] = v;
    }
    #pragma unroll
    for (int r = 0; r < 4; r++){
      float mn = fmaxf(mi[r], mx[r]);
      al[r] = exp2f(mi[r] - mn);
      mi[r] = mn;
      rs[r] = 0.f;
    }
    // P = exp2(s - m), packed 8-wide: lane's 8 ct-values -> contiguous col' = c*8+ct
    #pragma unroll
    for (int r = 0; r < 4; r++){
      int prow = w*16 + quad*4 + r;
      int pos = c ^ (prow & 7);
      u16x8 pk;
      #pragma unroll
      for (int ct = 0; ct < 8; ct++){
        float p = exp2f(sa[ct][r] - mi[r]);
        rs[r] += p;
        pk[ct] = f2bf(p);
      }
      *(u16x8*)&Ps[prow*128 + pos*8] = pk;
    }
    #pragma unroll
    for (int r = 0; r < 4; r++){
      float v = rs[r];
      #pragma unroll
      for (int off = 1; off < 16; off <<= 1)
        v += __shfl_xor(v, off, 64);
      li[r] = li[r] * al[r] + v;
    }
    #pragma unroll
    for (int dt = 0; dt < 4; dt++)
      #pragma unroll
      for (int r = 0; r < 4; r++)
        Oa[dt][r] *= al[r];

    // O += P V  (Ps rows wave-private: no barrier; compiler orders LDS w->r)
    #pragma unroll
    for (int ks = 0; ks < 4; ks++){
      int kc = ks*4 + quad;
      bf16x8 pf = *(const bf16x8*)&Ps[(w*16 + c)*128 + (kc ^ (c & 7))*8];
      #pragma unroll
      for (int dt = 0; dt < 4; dt++){
        int d = dt*16 + c;
        int pos = (kc & 8) | ((kc & 7) ^ (c & 7));
        bf16x8 vf = *(const bf16x8*)&Vts[d*128 + pos*8];
        Oa[dt] = __builtin_amdgcn_mfma_f32_16x16x32_bf16(pf, vf, Oa[dt], 0, 0, 0);
      }
    }
  }
  #pragma unroll
  for (int r = 0; r < 4; r++){
    float inv = __builtin_amdgcn_rcpf(li[r]);
    #pragma unroll
    for (int dt = 0; dt < 4; dt++){
      float v = Oa[dt][r] * inv;
      int srow = q0 + w*16 + quad*4 + r;
      int col  = h*64 + dt*16 + c;
      AO[(size_t)(b*2048 + srow)*1024 + col] = f2bf(v);
    }
  }
}

extern "C" void kernel_launch(void* const* d_in, const int* in_sizes, int n_in,
                              void* d_out, int out_size, void* d_ws, size_t ws_size,
                              hipStream_t stream){
  const float* X    = (const float*)d_in[0];
  const float* Wqkv = (const float*)d_in[1];
  const float* Wo   = (const float*)d_in[2];
  float* out = (float*)d_out;
  char* ws = (char*)d_ws;
  unsigned short* Xb    = (unsigned short*)(ws);
  unsigned short* Wqkvb = (unsigned short*)(ws + (size_t)8  * 1048576);
  unsigned short* Wob   = (unsigned short*)(ws + (size_t)14 * 1048576);
  unsigned short* QKVb  = (unsigned short*)(ws + (size_t)16 * 1048576);
  unsigned short* Qh    = (unsigned short*)(ws + (size_t)40 * 1048576);
  unsigned short* Kh    = (unsigned short*)(ws + (size_t)48 * 1048576);
  unsigned short* Vtp   = (unsigned short*)(ws + (size_t)56 * 1048576);
  unsigned short* AO    = (unsigned short*)(ws + (size_t)64 * 1048576);

  cast_kernel<<<4096, 256, 0, stream>>>(X,    Xb,    1048576);
  cast_kernel<<<3072, 256, 0, stream>>>(Wqkv, Wqkvb, 786432);
  cast_kernel<<<1024, 256, 0, stream>>>(Wo,   Wob,   262144);
  gemm_bt<1><<<dim3(24, 32), 256, 0, stream>>>(Xb, Wqkvb, QKVb, 4096, 3072, 1024);
  rope_kernel<<<8192, 256, 0, stream>>>(QKVb, Qh, Kh);
  vtrans_kernel<<<dim3(16, 2, 16), 256, 0, stream>>>(QKVb, Vtp);
  attn_kernel<<<512, 512, 0, stream>>>(Qh, Kh, Vtp, AO);
  gemm_bt<0><<<dim3(8, 32), 256, 0, stream>>>(AO, Wob, out, 4096, 1024, 1024);
}

// Round 4
// 186.224 us; speedup vs baseline: 1.5709x; 1.1611x over previous
//
#include <hip/hip_runtime.h>
#include <stdint.h>

// B=2, S=2048, D=1024, H=16, dh=64, THETA=10000
// cast3 -> QKV gemm -> rope(Q pre-scaled by log2e/8) + vtrans -> flash attn
// (S^T trick: PV via mfma_16x16x16 straight from registers, max-free softmax) -> out gemm

typedef __attribute__((ext_vector_type(8))) __bf16 bf16x8;
typedef __attribute__((ext_vector_type(8))) unsigned short u16x8;
typedef __attribute__((ext_vector_type(4))) short s16x4;
typedef __attribute__((ext_vector_type(4))) float f32x4;

__device__ __forceinline__ unsigned short f2bf(float f){
  unsigned int u = __float_as_uint(f);
  unsigned int r = (u + 0x7FFFu + ((u >> 16) & 1u)) >> 16;  // RNE
  return (unsigned short)r;
}
__device__ __forceinline__ float bf2f(unsigned short u){
  return __uint_as_float(((unsigned int)u) << 16);
}

// v_mfma_f32_16x16x16_bf16 (gfx950 per cdna4_isa §10). Builtin name is the
// gfx90a-lineage "...16bf16_1k". Host pass doesn't know amdgcn builtins ->
// stub it out (device-only execution).
__device__ __forceinline__ f32x4 mfma16(s16x4 a, s16x4 b, f32x4 c){
#if defined(__HIP_DEVICE_COMPILE__)
  return __builtin_amdgcn_mfma_f32_16x16x16bf16_1k(a, b, c, 0, 0, 0);
#else
  return c;
#endif
}

// async global->LDS, 16B per lane; LDS dest = wave-uniform base + lane*16
__device__ __forceinline__ void gld16(const unsigned short* g, unsigned short* l){
  __builtin_amdgcn_global_load_lds((const __attribute__((address_space(1))) unsigned int*)g,
                                   (__attribute__((address_space(3))) unsigned int*)l,
                                   16, 0, 0);
}

__global__ __launch_bounds__(256) void cast3_kernel(const float* __restrict__ a,
                                                    const float* __restrict__ b,
                                                    const float* __restrict__ c,
                                                    unsigned short* __restrict__ oa,
                                                    unsigned short* __restrict__ ob,
                                                    unsigned short* __restrict__ oc,
                                                    int na, int nb){
  int i = blockIdx.x * 256 + threadIdx.x;
  const float* in; unsigned short* out; int j = i;
  if (i < na){ in = a; out = oa; }
  else if (i < na + nb){ in = b; out = ob; j = i - na; }
  else { in = c; out = oc; j = i - na - nb; }
  float4 v = ((const float4*)in)[j];
  ushort4 o;
  o.x = f2bf(v.x); o.y = f2bf(v.y); o.z = f2bf(v.z); o.w = f2bf(v.w);
  ((ushort4*)out)[j] = o;
}

// C[M,N] = A[M,K] * W[N,K]^T, bf16, 128x128 tile, BK=64, async-LDS, XOR swizzle.
template<int WRITE_BF16>
__global__ __launch_bounds__(256) void gemm_bt(const unsigned short* __restrict__ A,
                                               const unsigned short* __restrict__ W,
                                               void* __restrict__ Cp,
                                               int M, int N, int K){
  __shared__ __align__(16) unsigned short As[128*64];
  __shared__ __align__(16) unsigned short Bs[128*64];
  const int tid  = threadIdx.x;
  const int lane = tid & 63, wave = tid >> 6;
  const int wr = wave >> 1, wc = wave & 1;
  const int quad = lane >> 4, c = lane & 15;
  const int m0 = blockIdx.y * 128, n0 = blockIdx.x * 128;

  const f32x4 z4 = {0.f, 0.f, 0.f, 0.f};
  f32x4 acc[4][4];
  #pragma unroll
  for (int i = 0; i < 4; i++)
    #pragma unroll
    for (int j = 0; j < 4; j++) acc[i][j] = z4;

  const int nk = K >> 6;
  for (int kt = 0; kt < nk; kt++){
    const int k0 = kt << 6;
    #pragma unroll
    for (int p = 0; p < 4; p++){
      int blk = p*4 + wave;
      int L = blk*64 + lane;
      int row = L >> 3;
      int sub = (L & 7) ^ (row & 7);
      gld16(&A[(size_t)(m0+row)*K + k0 + sub*8], &As[blk*512]);
      gld16(&W[(size_t)(n0+row)*K + k0 + sub*8], &Bs[blk*512]);
    }
    __syncthreads();
    #pragma unroll
    for (int ks = 0; ks < 2; ks++){
      bf16x8 af[4], bfr[4];
      #pragma unroll
      for (int i = 0; i < 4; i++){
        int row = wr*64 + i*16 + c;
        int pos = (ks*4 + quad) ^ (c & 7);
        af[i] = *(const bf16x8*)&As[row*64 + pos*8];
      }
      #pragma unroll
      for (int j = 0; j < 4; j++){
        int row = wc*64 + j*16 + c;
        int pos = (ks*4 + quad) ^ (c & 7);
        bfr[j] = *(const bf16x8*)&Bs[row*64 + pos*8];
      }
      #pragma unroll
      for (int i = 0; i < 4; i++)
        #pragma unroll
        for (int j = 0; j < 4; j++)
          acc[i][j] = __builtin_amdgcn_mfma_f32_16x16x32_bf16(af[i], bfr[j], acc[i][j], 0, 0, 0);
    }
    __syncthreads();
  }
  #pragma unroll
  for (int i = 0; i < 4; i++)
    #pragma unroll
    for (int j = 0; j < 4; j++)
      #pragma unroll
      for (int r = 0; r < 4; r++){
        int row = m0 + wr*64 + i*16 + quad*4 + r;
        int col = n0 + wc*64 + j*16 + c;
        float v = acc[i][j][r];
        if (WRITE_BF16) ((unsigned short*)Cp)[(size_t)row*N + col] = f2bf(v);
        else            ((float*)Cp)[(size_t)row*N + col] = v;
      }
}

// rope on Q,K: QKV (4096 x 3072) -> Qh/Kh [h][b][s][64]; Q pre-scaled by log2(e)/8
__global__ __launch_bounds__(256) void rope_kernel(const unsigned short* __restrict__ QKV,
                                                   unsigned short* __restrict__ Qh,
                                                   unsigned short* __restrict__ Kh){
  int tid = blockIdx.x * 256 + threadIdx.x;     // (b,s,h,p)
  int p = tid & 31;
  int h = (tid >> 5) & 15;
  int s = (tid >> 9) & 2047;
  int b = tid >> 20;
  size_t ibase = (size_t)(b*2048 + s) * 3072 + h*64 + 2*p;
  ushort2 q2 = *(const ushort2*)&QKV[ibase];
  ushort2 k2 = *(const ushort2*)&QKV[ibase + 1024];
  float freq = __expf(-(float)p * (9.210340371976184f / 32.0f));  // theta^(-p/32)
  float ang = (float)s * freq;
  float cs = cosf(ang), sn = sinf(ang);
  float qe = bf2f(q2.x), qo = bf2f(q2.y);
  float ke = bf2f(k2.x), ko = bf2f(k2.y);
  const float qs = 0.18033688011112042f;        // log2(e)/8 folded into Q
  ushort2 qn, kn;
  qn.x = f2bf((qe*cs - qo*sn)*qs); qn.y = f2bf((qe*sn + qo*cs)*qs);
  kn.x = f2bf(ke*cs - ko*sn);      kn.y = f2bf(ke*sn + ko*cs);
  size_t obase = (size_t)((h*2 + b)*2048 + s) * 64 + 2*p;
  *(ushort2*)&Qh[obase] = qn;
  *(ushort2*)&Kh[obase] = kn;
}

// V -> Vt [h][b][d=64][S] plain transpose (LDS-tiled, XOR-swizzled chunks)
__global__ __launch_bounds__(256) void vtrans_kernel(const unsigned short* __restrict__ QKV,
                                                     unsigned short* __restrict__ Vt){
  __shared__ __align__(16) unsigned short Vs[128*64];
  const int st = blockIdx.x, b = blockIdx.y, h = blockIdx.z;
  const int s0 = st * 128;
  const int tid = threadIdx.x;
  #pragma unroll
  for (int it = 0; it < 4; it++){
    int L = it*256 + tid;               // 1024 chunks of 8
    int r = L >> 3, sub = L & 7;
    int pos = sub ^ (r & 7) ^ ((r >> 3) & 7);
    *(u16x8*)&Vs[r*64 + pos*8] =
      *(const u16x8*)&QKV[(size_t)(b*2048 + s0 + r)*3072 + 2048 + h*64 + sub*8];
  }
  __syncthreads();
  const size_t obase = (size_t)((h*2 + b) * 64) * 2048;
  #pragma unroll
  for (int it = 0; it < 4; it++){
    int L = it*256 + tid;               // d(64) x s8(16)
    int d = L >> 4, s8 = L & 15;
    u16x8 pk;
    #pragma unroll
    for (int j = 0; j < 8; j++){
      int r = s8*8 + j;
      int pos = (d >> 3) ^ j ^ (s8 & 7);
      pk[j] = Vs[r*64 + pos*8 + (d & 7)];
    }
    *(u16x8*)&Vt[obase + (size_t)d*2048 + s0 + s8*8] = pk;
  }
}

// Flash attention, causal, S^T formulation. BQ=128 (8 waves x 16 q-rows), BKV=128.
// Ks[kv][d] (row-XOR-swizzled); Vts[d][kv] (chunk-XOR-swizzled). No P LDS buffer.
__global__ __launch_bounds__(512, 4) void attn_kernel(const unsigned short* __restrict__ Qh,
                                                      const unsigned short* __restrict__ Kh,
                                                      const unsigned short* __restrict__ Vt,
                                                      unsigned short* __restrict__ AO){
  __shared__ __align__(16) unsigned short Ks [128*64];   // 16 KB
  __shared__ __align__(16) unsigned short Vts[64*128];   // 16 KB
  const int bx = blockIdx.x;                 // 512 blocks; CU pairing: g and g+8 sum to 17 iters
  const int g  = bx >> 5;
  const int qt = (g < 8) ? (15 - g) : (g - 8);
  const int bh = bx & 31;
  const int h = bh >> 1, b = bh & 1;
  const int q0 = qt * 128;
  const int tid = threadIdx.x;
  const int lane = tid & 63, w = tid >> 6;
  const int quad = lane >> 4, c = lane & 15;
  const size_t hb = (size_t)(h*2 + b) * 2048 * 64;
  const unsigned short* qp = Qh + hb;
  const unsigned short* kp = Kh + hb;
  const unsigned short* vp = Vt + hb;

  bf16x8 qf[2];                               // Q fragments (B-operand layout)
  #pragma unroll
  for (int ks = 0; ks < 2; ks++)
    qf[ks] = *(const bf16x8*)&qp[(size_t)(q0 + w*16 + c)*64 + ks*32 + quad*8];

  const f32x4 z4 = {0.f, 0.f, 0.f, 0.f};
  float rs = 0.f;                             // per-lane row-sum (q = c), max-free
  f32x4 Oa[4];                                // O^T: lane holds O[d=dt*16+quad*4+r][q=c]
  #pragma unroll
  for (int dt = 0; dt < 4; dt++) Oa[dt] = z4;

  const int nkt = qt + 1;
  for (int kt = 0; kt < nkt; kt++){
    const int kv0 = kt * 128;
    const bool diag = (kt == qt);
    __syncthreads();
    #pragma unroll
    for (int p = 0; p < 2; p++){
      int blk = p*8 + w;
      int L = blk*64 + lane;
      {   // K tile: row = kv, 8 chunks of 8 along d, chunk XOR row&7
        int row = L >> 3;
        int sub = (L & 7) ^ (row & 7);
        gld16(&kp[(size_t)(kv0 + row)*64 + sub*8], &Ks[blk*512]);
      }
      {   // Vt tile: d rows, 16 chunks of 8 along kv, chunk XOR d&15
        int d = L >> 4;
        int mp = (L & 15) ^ (d & 15);
        gld16(&vp[(size_t)d*2048 + kv0 + mp*8], &Vts[blk*512]);
      }
    }
    __syncthreads();

    #pragma unroll
    for (int hk = 0; hk < 2; hk++){
      const int rlim = diag ? (w - 4*hk) : 3;   // wave-uniform causal tile skip
      if (rlim < 0) continue;
      // S^T tiles: sa[rt] holds S^T[kv = hk*64+rt*16+quad*4+r][q = w*16+c]
      f32x4 sa[4];
      #pragma unroll
      for (int rt = 0; rt < 4; rt++) sa[rt] = z4;
      #pragma unroll
      for (int ks = 0; ks < 2; ks++)
        #pragma unroll
        for (int rt = 0; rt < 4; rt++){
          if (rt > rlim) continue;
          int row = hk*64 + rt*16 + c;
          int pos = (ks*4 + quad) ^ (c & 7);
          bf16x8 kf = *(const bf16x8*)&Ks[row*64 + pos*8];
          sa[rt] = __builtin_amdgcn_mfma_f32_16x16x32_bf16(kf, qf[ks], sa[rt], 0, 0, 0);
        }
      #pragma unroll
      for (int rt = 0; rt < 4; rt++){
        if (rt > rlim) continue;
        if (diag && rt == rlim){               // boundary 16x16: mask kv > q
          #pragma unroll
          for (int r = 0; r < 4; r++){
            int kvl = hk*64 + rt*16 + quad*4 + r;
            sa[rt][r] = (kvl > w*16 + c) ? -3.0e38f : sa[rt][r];
          }
        }
        s16x4 pf;
        #pragma unroll
        for (int r = 0; r < 4; r++){
          float p = exp2f(sa[rt][r]);          // scale pre-folded into Q
          rs += p;
          pf[r] = (short)f2bf(p);
        }
        const int kvt = hk*4 + rt;
        #pragma unroll
        for (int dt = 0; dt < 4; dt++){
          int d = dt*16 + c;
          int mp = (kvt*2 + (quad >> 1)) ^ (d & 15);
          s16x4 vf = *(const s16x4*)&Vts[d*128 + mp*8 + (quad & 1)*4];
          Oa[dt] = mfma16(vf, pf, Oa[dt]);     // A=V^T (m=d), B=P^T (n=q)
        }
      }
    }
  }
  // row-sum across the 4 quads sharing q=c, then normalize and store O
  rs += __shfl_xor(rs, 16, 64);
  rs += __shfl_xor(rs, 32, 64);
  float inv = __builtin_amdgcn_rcpf(rs);
  const int srow = q0 + w*16 + c;
  #pragma unroll
  for (int dt = 0; dt < 4; dt++){
    ushort4 o;
    o.x = f2bf(Oa[dt][0] * inv);
    o.y = f2bf(Oa[dt][1] * inv);
    o.z = f2bf(Oa[dt][2] * inv);
    o.w = f2bf(Oa[dt][3] * inv);
    *(ushort4*)&AO[(size_t)(b*2048 + srow)*1024 + h*64 + dt*16 + quad*4] = o;
  }
}

extern "C" void kernel_launch(void* const* d_in, const int* in_sizes, int n_in,
                              void* d_out, int out_size, void* d_ws, size_t ws_size,
                              hipStream_t stream){
  const float* X    = (const float*)d_in[0];
  const float* Wqkv = (const float*)d_in[1];
  const float* Wo   = (const float*)d_in[2];
  float* out = (float*)d_out;
  char* ws = (char*)d_ws;
  unsigned short* Xb    = (unsigned short*)(ws);
  unsigned short* Wqkvb = (unsigned short*)(ws + (size_t)8  * 1048576);
  unsigned short* Wob   = (unsigned short*)(ws + (size_t)14 * 1048576);
  unsigned short* QKVb  = (unsigned short*)(ws + (size_t)16 * 1048576);
  unsigned short* Qh    = (unsigned short*)(ws + (size_t)40 * 1048576);
  unsigned short* Kh    = (unsigned short*)(ws + (size_t)48 * 1048576);
  unsigned short* Vt    = (unsigned short*)(ws + (size_t)56 * 1048576);
  unsigned short* AO    = (unsigned short*)(ws + (size_t)64 * 1048576);

  cast3_kernel<<<8192, 256, 0, stream>>>(X, Wqkv, Wo, Xb, Wqkvb, Wob, 1048576, 786432);
  gemm_bt<1><<<dim3(24, 32), 256, 0, stream>>>(Xb, Wqkvb, QKVb, 4096, 3072, 1024);
  rope_kernel<<<8192, 256, 0, stream>>>(QKVb, Qh, Kh);
  vtrans_kernel<<<dim3(16, 2, 16), 256, 0, stream>>>(QKVb, Vt);
  attn_kernel<<<512, 512, 0, stream>>>(Qh, Kh, Vt, AO);
  gemm_bt<0><<<dim3(8, 32), 256, 0, stream>>>(AO, Wob, out, 4096, 1024, 1024);
}

// Round 5
// 182.302 us; speedup vs baseline: 1.6047x; 1.0215x over previous
//
#include <hip/hip_runtime.h>
#include <stdint.h>

// B=2, S=2048, D=1024, H=16, dh=64, THETA=10000
// cast3 -> QKV gemm -> rope(Q pre-scaled by log2e/8) + vtrans(pi-permuted) ->
// flash attn (S^T, PV via mfma_16x16x32 from registers, max-free softmax) -> out gemm

typedef __attribute__((ext_vector_type(8))) __bf16 bf16x8;
typedef __attribute__((ext_vector_type(8))) unsigned short u16x8;
typedef __attribute__((ext_vector_type(4))) float f32x4;

__device__ __forceinline__ unsigned short f2bf(float f){
  unsigned int u = __float_as_uint(f);
  unsigned int r = (u + 0x7FFFu + ((u >> 16) & 1u)) >> 16;  // RNE
  return (unsigned short)r;
}
__device__ __forceinline__ float bf2f(unsigned short u){
  return __uint_as_float(((unsigned int)u) << 16);
}
// pack two fp32 -> two bf16 (truncate) in one v_perm_b32
__device__ __forceinline__ unsigned int pack_bf2(float lo, float hi){
  return __builtin_amdgcn_perm(__float_as_uint(hi), __float_as_uint(lo), 0x07060302u);
}

// async global->LDS, 16B per lane; LDS dest = wave-uniform base + lane*16
__device__ __forceinline__ void gld16(const unsigned short* g, unsigned short* l){
  __builtin_amdgcn_global_load_lds((const __attribute__((address_space(1))) unsigned int*)g,
                                   (__attribute__((address_space(3))) unsigned int*)l,
                                   16, 0, 0);
}

__global__ __launch_bounds__(256) void cast3_kernel(const float* __restrict__ a,
                                                    const float* __restrict__ b,
                                                    const float* __restrict__ c,
                                                    unsigned short* __restrict__ oa,
                                                    unsigned short* __restrict__ ob,
                                                    unsigned short* __restrict__ oc,
                                                    int na, int nb){
  int i = blockIdx.x * 256 + threadIdx.x;
  const float* in; unsigned short* out; int j = i;
  if (i < na){ in = a; out = oa; }
  else if (i < na + nb){ in = b; out = ob; j = i - na; }
  else { in = c; out = oc; j = i - na - nb; }
  float4 v = ((const float4*)in)[j];
  ushort4 o;
  o.x = f2bf(v.x); o.y = f2bf(v.y); o.z = f2bf(v.z); o.w = f2bf(v.w);
  ((ushort4*)out)[j] = o;
}

// C[M,N] = A[M,K] * W[N,K]^T, bf16, 128x128 tile, BK=64, async-LDS, XOR swizzle.
template<int WRITE_BF16>
__global__ __launch_bounds__(256) void gemm_bt(const unsigned short* __restrict__ A,
                                               const unsigned short* __restrict__ W,
                                               void* __restrict__ Cp,
                                               int M, int N, int K){
  __shared__ __align__(16) unsigned short As[128*64];
  __shared__ __align__(16) unsigned short Bs[128*64];
  const int tid  = threadIdx.x;
  const int lane = tid & 63, wave = tid >> 6;
  const int wr = wave >> 1, wc = wave & 1;
  const int quad = lane >> 4, c = lane & 15;
  const int m0 = blockIdx.y * 128, n0 = blockIdx.x * 128;

  const f32x4 z4 = {0.f, 0.f, 0.f, 0.f};
  f32x4 acc[4][4];
  #pragma unroll
  for (int i = 0; i < 4; i++)
    #pragma unroll
    for (int j = 0; j < 4; j++) acc[i][j] = z4;

  const int nk = K >> 6;
  for (int kt = 0; kt < nk; kt++){
    const int k0 = kt << 6;
    #pragma unroll
    for (int p = 0; p < 4; p++){
      int blk = p*4 + wave;
      int L = blk*64 + lane;
      int row = L >> 3;
      int sub = (L & 7) ^ (row & 7);
      gld16(&A[(size_t)(m0+row)*K + k0 + sub*8], &As[blk*512]);
      gld16(&W[(size_t)(n0+row)*K + k0 + sub*8], &Bs[blk*512]);
    }
    __syncthreads();
    #pragma unroll
    for (int ks = 0; ks < 2; ks++){
      bf16x8 af[4], bfr[4];
      #pragma unroll
      for (int i = 0; i < 4; i++){
        int row = wr*64 + i*16 + c;
        int pos = (ks*4 + quad) ^ (c & 7);
        af[i] = *(const bf16x8*)&As[row*64 + pos*8];
      }
      #pragma unroll
      for (int j = 0; j < 4; j++){
        int row = wc*64 + j*16 + c;
        int pos = (ks*4 + quad) ^ (c & 7);
        bfr[j] = *(const bf16x8*)&Bs[row*64 + pos*8];
      }
      #pragma unroll
      for (int i = 0; i < 4; i++)
        #pragma unroll
        for (int j = 0; j < 4; j++)
          acc[i][j] = __builtin_amdgcn_mfma_f32_16x16x32_bf16(af[i], bfr[j], acc[i][j], 0, 0, 0);
    }
    __syncthreads();
  }
  #pragma unroll
  for (int i = 0; i < 4; i++)
    #pragma unroll
    for (int j = 0; j < 4; j++)
      #pragma unroll
      for (int r = 0; r < 4; r++){
        int row = m0 + wr*64 + i*16 + quad*4 + r;
        int col = n0 + wc*64 + j*16 + c;
        float v = acc[i][j][r];
        if (WRITE_BF16) ((unsigned short*)Cp)[(size_t)row*N + col] = f2bf(v);
        else            ((float*)Cp)[(size_t)row*N + col] = v;
      }
}

// out gemm: 64M x 128N tile (512 blocks -> 2/CU so barrier drains overlap), fp32 out.
__global__ __launch_bounds__(256) void gemm_o(const unsigned short* __restrict__ A,
                                              const unsigned short* __restrict__ W,
                                              float* __restrict__ Cp,
                                              int M, int N, int K){
  __shared__ __align__(16) unsigned short As[64*64];
  __shared__ __align__(16) unsigned short Bs[128*64];
  const int tid  = threadIdx.x;
  const int lane = tid & 63, wave = tid >> 6;
  const int wr = wave >> 1, wc = wave & 1;
  const int quad = lane >> 4, c = lane & 15;
  const int m0 = blockIdx.y * 64, n0 = blockIdx.x * 128;

  const f32x4 z4 = {0.f, 0.f, 0.f, 0.f};
  f32x4 acc[2][4];
  #pragma unroll
  for (int i = 0; i < 2; i++)
    #pragma unroll
    for (int j = 0; j < 4; j++) acc[i][j] = z4;

  const int nk = K >> 6;
  for (int kt = 0; kt < nk; kt++){
    const int k0 = kt << 6;
    #pragma unroll
    for (int p = 0; p < 2; p++){      // As: 512 chunks
      int blk = p*4 + wave;
      int L = blk*64 + lane;
      int row = L >> 3;
      int sub = (L & 7) ^ (row & 7);
      gld16(&A[(size_t)(m0+row)*K + k0 + sub*8], &As[blk*512]);
    }
    #pragma unroll
    for (int p = 0; p < 4; p++){      // Bs: 1024 chunks
      int blk = p*4 + wave;
      int L = blk*64 + lane;
      int row = L >> 3;
      int sub = (L & 7) ^ (row & 7);
      gld16(&W[(size_t)(n0+row)*K + k0 + sub*8], &Bs[blk*512]);
    }
    __syncthreads();
    #pragma unroll
    for (int ks = 0; ks < 2; ks++){
      bf16x8 af[2], bfr[4];
      #pragma unroll
      for (int i = 0; i < 2; i++){
        int row = wr*32 + i*16 + c;
        int pos = (ks*4 + quad) ^ (c & 7);
        af[i] = *(const bf16x8*)&As[row*64 + pos*8];
      }
      #pragma unroll
      for (int j = 0; j < 4; j++){
        int row = wc*64 + j*16 + c;
        int pos = (ks*4 + quad) ^ (c & 7);
        bfr[j] = *(const bf16x8*)&Bs[row*64 + pos*8];
      }
      #pragma unroll
      for (int i = 0; i < 2; i++)
        #pragma unroll
        for (int j = 0; j < 4; j++)
          acc[i][j] = __builtin_amdgcn_mfma_f32_16x16x32_bf16(af[i], bfr[j], acc[i][j], 0, 0, 0);
    }
    __syncthreads();
  }
  #pragma unroll
  for (int i = 0; i < 2; i++)
    #pragma unroll
    for (int j = 0; j < 4; j++)
      #pragma unroll
      for (int r = 0; r < 4; r++){
        int row = m0 + wr*32 + i*16 + quad*4 + r;
        int col = n0 + wc*64 + j*16 + c;
        Cp[(size_t)row*N + col] = acc[i][j][r];
      }
}

// rope on Q,K: QKV (4096 x 3072) -> Qh/Kh [h][b][s][64]; Q pre-scaled by log2(e)/8
__global__ __launch_bounds__(256) void rope_kernel(const unsigned short* __restrict__ QKV,
                                                   unsigned short* __restrict__ Qh,
                                                   unsigned short* __restrict__ Kh){
  int tid = blockIdx.x * 256 + threadIdx.x;     // (b,s,h,p)
  int p = tid & 31;
  int h = (tid >> 5) & 15;
  int s = (tid >> 9) & 2047;
  int b = tid >> 20;
  size_t ibase = (size_t)(b*2048 + s) * 3072 + h*64 + 2*p;
  ushort2 q2 = *(const ushort2*)&QKV[ibase];
  ushort2 k2 = *(const ushort2*)&QKV[ibase + 1024];
  float freq = __expf(-(float)p * (9.210340371976184f / 32.0f));  // theta^(-p/32)
  float ang = (float)s * freq;
  float cs = cosf(ang), sn = sinf(ang);
  float qe = bf2f(q2.x), qo = bf2f(q2.y);
  float ke = bf2f(k2.x), ko = bf2f(k2.y);
  const float qs = 0.18033688011112042f;        // log2(e)/8 folded into Q
  ushort2 qn, kn;
  qn.x = f2bf((qe*cs - qo*sn)*qs); qn.y = f2bf((qe*sn + qo*cs)*qs);
  kn.x = f2bf(ke*cs - ko*sn);      kn.y = f2bf(ke*sn + ko*cs);
  size_t obase = (size_t)((h*2 + b)*2048 + s) * 64 + 2*p;
  *(ushort2*)&Qh[obase] = qn;
  *(ushort2*)&Kh[obase] = kn;
}

// V -> Vtp [h][b][d=64][S], transposed AND pi-permuted within each 32-kv chunk:
// Vtp[d][C*32 + kt] = V[C*32 + pi(kt)][d], pi(kt = q8*8 + j) = (j>>2)*16 + q8*4 + (j&3)
__global__ __launch_bounds__(256) void vtrans_kernel(const unsigned short* __restrict__ QKV,
                                                     unsigned short* __restrict__ Vtp){
  __shared__ __align__(16) unsigned short Vs[128*64];
  const int st = blockIdx.x, b = blockIdx.y, h = blockIdx.z;
  const int s0 = st * 128;
  const int tid = threadIdx.x;
  #pragma unroll
  for (int it = 0; it < 4; it++){
    int L = it*256 + tid;               // 1024 chunks of 8
    int r = L >> 3, sub = L & 7;
    int pos = sub ^ (r & 7) ^ ((r >> 3) & 7);
    *(u16x8*)&Vs[r*64 + pos*8] =
      *(const u16x8*)&QKV[(size_t)(b*2048 + s0 + r)*3072 + 2048 + h*64 + sub*8];
  }
  __syncthreads();
  const size_t obase = (size_t)((h*2 + b) * 64) * 2048;
  #pragma unroll
  for (int it = 0; it < 4; it++){
    int L = it*256 + tid;               // d(64) x g8(16)
    int d = L >> 4, g8 = L & 15;
    int C = g8 >> 2, q8 = g8 & 3;       // chunk, quad-within-chunk
    u16x8 pk;
    #pragma unroll
    for (int j = 0; j < 8; j++){
      int r = C*32 + ((j >> 2) << 4) + q8*4 + (j & 3);   // pi
      int pos = (d >> 3) ^ (r & 7) ^ ((r >> 3) & 7);
      pk[j] = Vs[r*64 + pos*8 + (d & 7)];
    }
    *(u16x8*)&Vtp[obase + (size_t)d*2048 + s0 + g8*8] = pk;
  }
}

// Flash attention, causal, S^T formulation. BQ=128 (8 waves x 16 q-rows), BKV=128.
// Ks[kv][d] row-XOR-swizzled; Vts[d][kv~] chunk-XOR-swizzled (kv~ = pi-permuted).
__global__ __launch_bounds__(512, 6) void attn_kernel(const unsigned short* __restrict__ Qh,
                                                      const unsigned short* __restrict__ Kh,
                                                      const unsigned short* __restrict__ Vtp,
                                                      unsigned short* __restrict__ AO){
  __shared__ __align__(16) unsigned short Ks [128*64];   // 16 KB
  __shared__ __align__(16) unsigned short Vts[64*128];   // 16 KB
  const int bx = blockIdx.x;                 // 512 blocks; pairing: g and g+8 sum to 17 iters
  const int g  = bx >> 5;
  const int qt = (g < 8) ? (15 - g) : (g - 8);
  const int bh = bx & 31;
  const int h = bh >> 1, b = bh & 1;
  const int q0 = qt * 128;
  const int tid = threadIdx.x;
  const int lane = tid & 63, w = tid >> 6;
  const int quad = lane >> 4, c = lane & 15;
  const size_t hb = (size_t)(h*2 + b) * 2048 * 64;
  const unsigned short* qp = Qh + hb;
  const unsigned short* kp = Kh + hb;
  const unsigned short* vp = Vtp + hb;

  bf16x8 qf[2];                               // Q fragments (B-operand layout)
  #pragma unroll
  for (int ks = 0; ks < 2; ks++)
    qf[ks] = *(const bf16x8*)&qp[(size_t)(q0 + w*16 + c)*64 + ks*32 + quad*8];

  const f32x4 z4 = {0.f, 0.f, 0.f, 0.f};
  float rs = 0.f;                             // per-lane row-sum (q = c), max-free
  f32x4 Oa[4];                                // O^T: lane holds O[d=dt*16+quad*4+r][q=c]
  #pragma unroll
  for (int dt = 0; dt < 4; dt++) Oa[dt] = z4;

  const int nkt = qt + 1;
  for (int kt = 0; kt < nkt; kt++){
    const int kv0 = kt * 128;
    const bool diag = (kt == qt);
    __syncthreads();
    #pragma unroll
    for (int p = 0; p < 2; p++){
      int blk = p*8 + w;
      int L = blk*64 + lane;
      {   // K tile: row = kv, 8 chunks of 8 along d, chunk XOR row&7
        int row = L >> 3;
        int sub = (L & 7) ^ (row & 7);
        gld16(&kp[(size_t)(kv0 + row)*64 + sub*8], &Ks[blk*512]);
      }
      {   // Vt tile: d rows, 16 chunks of 8 along kv~, chunk XOR d&15
        int d = L >> 4;
        int mp = (L & 15) ^ (d & 15);
        gld16(&vp[(size_t)d*2048 + kv0 + mp*8], &Vts[blk*512]);
      }
    }
    __syncthreads();

    #pragma unroll
    for (int hk = 0; hk < 2; hk++){
      const int rlim = diag ? (w - 4*hk) : 3;   // wave-uniform causal tile skip
      if (rlim < 0) continue;
      // S^T tiles: sa[rt] holds S^T[kv = hk*64+rt*16+quad*4+r][q = w*16+c]
      f32x4 sa[4];
      #pragma unroll
      for (int rt = 0; rt < 4; rt++) sa[rt] = z4;
      #pragma unroll
      for (int ks = 0; ks < 2; ks++)
        #pragma unroll
        for (int rt = 0; rt < 4; rt++){
          if (rt > rlim) continue;
          int row = hk*64 + rt*16 + c;
          int pos = (ks*4 + quad) ^ (c & 7);
          bf16x8 kf = *(const bf16x8*)&Ks[row*64 + pos*8];
          sa[rt] = __builtin_amdgcn_mfma_f32_16x16x32_bf16(kf, qf[ks], sa[rt], 0, 0, 0);
        }
      // softmax (max-free): psv[rt] = exp2(sa[rt]); 0 for skipped tiles
      f32x4 psv[4];
      #pragma unroll
      for (int rt = 0; rt < 4; rt++) psv[rt] = z4;
      #pragma unroll
      for (int rt = 0; rt < 4; rt++){
        if (rt > rlim) continue;
        if (diag && rt == rlim){               // boundary 16x16: mask kv > q
          #pragma unroll
          for (int r = 0; r < 4; r++){
            int kvl = hk*64 + rt*16 + quad*4 + r;
            sa[rt][r] = (kvl > w*16 + c) ? -3.0e38f : sa[rt][r];
          }
        }
        #pragma unroll
        for (int r = 0; r < 4; r++){
          float p = exp2f(sa[rt][r]);          // scale pre-folded into Q
          rs += p;
          psv[rt][r] = p;
        }
      }
      // PV in 32-kv chunks: pf8 = [psv[2ck] | psv[2ck+1]] matches pi-permuted Vts
      #pragma unroll
      for (int ck = 0; ck < 2; ck++){
        if (2*ck > rlim) continue;
        union { unsigned int u[4]; bf16x8 v; } pf;
        pf.u[0] = pack_bf2(psv[2*ck][0],   psv[2*ck][1]);
        pf.u[1] = pack_bf2(psv[2*ck][2],   psv[2*ck][3]);
        pf.u[2] = pack_bf2(psv[2*ck+1][0], psv[2*ck+1][1]);
        pf.u[3] = pack_bf2(psv[2*ck+1][2], psv[2*ck+1][3]);
        const int m8 = hk*8 + ck*4 + quad;     // chunk-of-8 index along kv~
        #pragma unroll
        for (int dt = 0; dt < 4; dt++){
          int d = dt*16 + c;
          int pos = m8 ^ c;                    // d & 15 == c
          bf16x8 vf = *(const bf16x8*)&Vts[d*128 + pos*8];
          Oa[dt] = __builtin_amdgcn_mfma_f32_16x16x32_bf16(vf, pf.v, Oa[dt], 0, 0, 0);
        }
      }
    }
  }
  // row-sum across the 4 quads sharing q=c, then normalize and store O
  rs += __shfl_xor(rs, 16, 64);
  rs += __shfl_xor(rs, 32, 64);
  float inv = __builtin_amdgcn_rcpf(rs);
  const int srow = q0 + w*16 + c;
  #pragma unroll
  for (int dt = 0; dt < 4; dt++){
    ushort4 o;
    o.x = f2bf(Oa[dt][0] * inv);
    o.y = f2bf(Oa[dt][1] * inv);
    o.z = f2bf(Oa[dt][2] * inv);
    o.w = f2bf(Oa[dt][3] * inv);
    *(ushort4*)&AO[(size_t)(b*2048 + srow)*1024 + h*64 + dt*16 + quad*4] = o;
  }
}

extern "C" void kernel_launch(void* const* d_in, const int* in_sizes, int n_in,
                              void* d_out, int out_size, void* d_ws, size_t ws_size,
                              hipStream_t stream){
  const float* X    = (const float*)d_in[0];
  const float* Wqkv = (const float*)d_in[1];
  const float* Wo   = (const float*)d_in[2];
  float* out = (float*)d_out;
  char* ws = (char*)d_ws;
  unsigned short* Xb    = (unsigned short*)(ws);
  unsigned short* Wqkvb = (unsigned short*)(ws + (size_t)8  * 1048576);
  unsigned short* Wob   = (unsigned short*)(ws + (size_t)14 * 1048576);
  unsigned short* QKVb  = (unsigned short*)(ws + (size_t)16 * 1048576);
  unsigned short* Qh    = (unsigned short*)(ws + (size_t)40 * 1048576);
  unsigned short* Kh    = (unsigned short*)(ws + (size_t)48 * 1048576);
  unsigned short* Vtp   = (unsigned short*)(ws + (size_t)56 * 1048576);
  unsigned short* AO    = (unsigned short*)(ws + (size_t)64 * 1048576);

  cast3_kernel<<<8192, 256, 0, stream>>>(X, Wqkv, Wo, Xb, Wqkvb, Wob, 1048576, 786432);
  gemm_bt<1><<<dim3(24, 32), 256, 0, stream>>>(Xb, Wqkvb, QKVb, 4096, 3072, 1024);
  rope_kernel<<<8192, 256, 0, stream>>>(QKVb, Qh, Kh);
  vtrans_kernel<<<dim3(16, 2, 16), 256, 0, stream>>>(QKVb, Vtp);
  attn_kernel<<<512, 512, 0, stream>>>(Qh, Kh, Vtp, AO);
  gemm_o<<<dim3(8, 64), 256, 0, stream>>>(AO, Wob, out, 4096, 1024, 1024);
}